// Round 14
// baseline (153.239 us; speedup 1.0000x reference)
//
#include <hip/hip_runtime.h>
#include <stdint.h>

#define CIN 256
#define COUT 128
#define BATCH 8
#define HH 64
#define WW 64
#define XROW 66

// xb2: padded bf16 input, [B][66 rows][66 cols][4 cb][8 slot][8 ch], slot pre-swizzled by (col&7)
#define XB2_BYTES ((size_t)BATCH * XROW * XROW * CIN * 2)
// gw3: fused weights, UNSWIZZLED: [9 taps][2 py][4 cb][256 row=co*2+px][8 g][8 ch]
#define GW3_BYTES ((size_t)9 * 2 * 4 * 256 * 64 * 2)

typedef __bf16 bf16x8 __attribute__((ext_vector_type(8)));
typedef float f32x4 __attribute__((ext_vector_type(4)));

__device__ __forceinline__ unsigned short f2bf(float f) {
  unsigned int u = __float_as_uint(f);
  u += 0x7fffu + ((u >> 16) & 1u);
  return (unsigned short)(u >> 16);
}

__device__ __forceinline__ void gload_lds16(const void* g, void* l) {
  __builtin_amdgcn_global_load_lds(
      (__attribute__((address_space(1))) void*)(uintptr_t)g,
      (__attribute__((address_space(3))) void*)l, 16, 0, 0);
}

// ---------------- fused prep: prep_x (512 blk) + prep_w (128 blk) + border (260 blk) ----------------
__global__ __launch_bounds__(256) void prep_all(const float* __restrict__ x,
                                                const float* __restrict__ w,
                                                const float* __restrict__ f,
                                                unsigned short* __restrict__ xb2,
                                                unsigned short* __restrict__ gw3) {
  __shared__ __align__(16) unsigned short lds[64][264];  // prep_x staging; fs aliases it
  const int blk = blockIdx.x;
  const int t = threadIdx.x;

  if (blk < 512) {
    // ---- prep_x: x -> padded channel-last swizzled bf16 (interior) ----
    int b = blk >> 6, iy = blk & 63;
    int cq = t >> 6, ix = t & 63;
    for (int ci = 0; ci < 64; ++ci) {
      int c = ci * 4 + cq;
      float v = x[(((size_t)b * CIN + c) * HH + iy) * WW + ix];
      lds[ix][c] = f2bf(v);
    }
    __syncthreads();
    for (int it = 0; it < 8; ++it) {
      int u = it * 256 + t;  // 2048 units of 16B: 64 ix * 32 (cb,slot)
      int ixo = u >> 5;
      int q = u & 31, cb = q >> 3, slot = q & 7;
      int col = ixo + 1;  // padded col
      int c0 = cb * 64 + 8 * (slot ^ (col & 7));
      uint4 val = *reinterpret_cast<const uint4*>(&lds[ixo][c0]);
      size_t o = ((((size_t)(b * XROW + (iy + 1)) * XROW + col) * 4 + cb) * 8 + slot) * 8;
      *reinterpret_cast<uint4*>(&xb2[o]) = val;
    }
  } else if (blk < 640) {
    // ---- prep_w: fuse He-scale * conv3x3 (x) FIR; stored UNSWIZZLED [row][g][8ch] ----
    float* fs = (float*)lds;
    int co = blk - 512;
    int c = t;
    if (c < 16) fs[c] = f[c];
    __syncthreads();
    float wl[3][3];
    const float he = 1.0f / 48.0f;  // 1/sqrt(256*9)
#pragma unroll
    for (int dy = 0; dy < 3; ++dy)
#pragma unroll
      for (int dx = 0; dx < 3; ++dx)
        wl[dy][dx] = w[((size_t)(co * CIN + c) * 3 + dy) * 3 + dx] * he;
    int cb = c >> 6, cl = c & 63;
    int g = cl >> 3;
    int ce = cl & 7;
    for (int d = 0; d < 3; ++d)
      for (int e = 0; e < 3; ++e)
        for (int py = 0; py < 2; ++py)
          for (int px = 0; px < 2; ++px) {
            int ty = 2 * d + 1 - py, tx = 2 * e + 1 - px;  // taps of 6x6 composite g
            float acc = 0.f;
            for (int dy = 0; dy < 3; ++dy) {
              int a = ty - dy;
              if (a < 0 || a > 3) continue;
              for (int dx = 0; dx < 3; ++dx) {
                int bb = tx - dx;
                if (bb < 0 || bb > 3) continue;
                acc += wl[dy][dx] * fs[a * 4 + bb];
              }
            }
            int row = co * 2 + px;
            size_t o =
                ((((size_t)(d * 3 + e) * 2 + py) * 4 + cb) * 256 + row) * 64 + g * 8 + ce;
            gw3[o] = f2bf(acc);
          }
  } else {
    // ---- border zeroing ----
    int u = (blk - 640) * 256 + t;
    if (u >= 66560) return;
    int b = u / 8320, v = u - b * 8320;
    int row, col, cs;
    if (v < 4224) {
      int rr = v / 2112;
      int rem = v - rr * 2112;
      row = rr * 65; col = rem >> 5; cs = rem & 31;
    } else {
      int v2 = v - 4224;
      row = 1 + (v2 >> 6);
      int rem = v2 & 63;
      col = (rem >> 5) * 65; cs = rem & 31;
    }
    size_t o = (((size_t)(b * XROW + row) * XROW + col) * 32 + cs) * 8;
    *reinterpret_cast<uint4*>(&xb2[o]) = make_uint4(0, 0, 0, 0);
  }
}

// ---------------- main: implicit-GEMM polyphase conv ----------------
// BM=128 (weight rows mb*128..+127), BN=256 (4 out sub-rows), 4 waves (1M x 4N),
// wave tile 128x64. A (weights) GLOBAL->REGISTER: all 4 waves read the same 16KB
// L2-resident tap tile (L1-amplified); LDS pipe carries ONLY bv (8 reads/step/wave
// = 768cy/CU << MFMA 2483cy/CU — R13 was LDS+MFMA balanced at 2304+2483). af
// double-buffered one phase ahead (plain C++ loads, compiler-counted waits; R9's
// spill trap avoided: ~230 VGPR < 256 cap). X single-buffered in LDS (50.7KB ->
// 2 blocks/CU, independent barrier groups hide residual latency per R13);
// NO per-step barriers — X is read-only within each 9-step cb window;
// __syncthreads only at the 4 cb boundaries.
__global__ __launch_bounds__(256, 2) void conv_main(
    const unsigned short* __restrict__ xb2,
    const unsigned short* __restrict__ gw3,
    const float* __restrict__ bias,
    float* __restrict__ out) {
  __shared__ __align__(16) unsigned char smem[50688];
  unsigned short* xt = (unsigned short*)smem;  // X: [6 xrow][66 col][8 slot][16B]

  const int bid = blockIdx.x;
  const int b = bid & 7;              // XCD b-affinity
  const int mg = (bid >> 3) & 15;
  const int mb = (bid >> 7) & 1;      // weight-row half
  const int py = (bid >> 8) & 1;
  const int m0 = mg * 4;              // 4 output sub-rows per block

  const int t = threadIdx.x;
  const int lane = t & 63;
  const int wn = t >> 6;              // wave 0..3 = output sub-row
  const int l15 = lane & 15, l4 = lane >> 4;

  f32x4 acc[8][4] = {};
  bf16x8 afA[8], afB[8];  // phase double-buffer (k-half granularity)

  const char* xbase = (const char*)xb2 + (size_t)((b * XROW + m0) * (XROW * 32)) * 16;
  const char* gw3b = (const char*)gw3 + mb * 16384;
  const int afbase = l15 * 128 + l4 * 16;  // + k8*64 + i*2048

  // X tile per cb: 6 rows x 66 cols x 8 slots = 3168 16B units; 13 iters of 256
#define STAGE_X(cb_)                                                          \
  do {                                                                        \
    int rr_ = 0, rem_ = t;                                                    \
    for (int it = 0; it < 13; ++it) {                                         \
      int u = it * 256 + t;                                                   \
      if (u < 3168) {                                                         \
        int col = rem_ >> 3, slot = rem_ & 7;                                 \
        size_t go = (size_t)(rr_ * XROW + col) * 32 + (cb_)*8 + slot;         \
        gload_lds16(xbase + go * 16, (char*)xt + (size_t)u * 16);             \
      }                                                                       \
      rem_ += 256;                                                            \
      if (rem_ >= 528) { rem_ -= 528; ++rr_; }                                \
    }                                                                         \
  } while (0)

  // af: 8 fragments from global (L1/L2); plain loads -> compiler-counted waits
#define LOAD_AF_G(DST, GP, K8)                                                         \
  do {                                                                                 \
    _Pragma("unroll") for (int i = 0; i < 8; ++i)                                      \
        (DST)[i] = *(const bf16x8*)((GP) + afbase + (K8)*64 + i * 2048);               \
  } while (0)

#define READ_BV(BV, K8)                                                                \
  do {                                                                                 \
    _Pragma("unroll") for (int j = 0; j < 4; ++j) {                                    \
      int col = j * 16 + l15 + e;                                                      \
      int slot = ((K8)*4 + l4) ^ (col & 7);                                            \
      (BV)[j] = *(const bf16x8*)(xt + ((size_t)xr * 66 + col) * 64 + slot * 8);        \
    }                                                                                  \
  } while (0)

#define MFMA32(AF, BV)                                                                   \
  do {                                                                                   \
    asm volatile("s_waitcnt lgkmcnt(0)" ::: "memory");                                   \
    __builtin_amdgcn_sched_barrier(0);                                                   \
    __builtin_amdgcn_s_setprio(1);                                                       \
    _Pragma("unroll") for (int i = 0; i < 8; ++i)                                        \
      _Pragma("unroll") for (int j = 0; j < 4; ++j)                                      \
        acc[i][j] =                                                                      \
            __builtin_amdgcn_mfma_f32_16x16x32_bf16((AF)[i], (BV)[j], acc[i][j], 0, 0, 0); \
    __builtin_amdgcn_s_setprio(0);                                                       \
  } while (0)

  // prologue: X(cb=0) staged; af k0 of step 0 in flight
  STAGE_X(0);
  {
    const char* g0 = gw3b + (((size_t)py * 4) << 15);  // de=0, cb=0
    LOAD_AF_G(afA, g0, 0);
  }
  __syncthreads();  // drains gload_lds (vmcnt 0) + fences X for all waves

  int cb = 0, de = 0, d = 0, e = 0;
  for (int s = 0; s < 36; ++s) {
    const int xr = wn + d;
    const int nde = (de == 8) ? 0 : de + 1;
    const int ncb = (de == 8) ? cb + 1 : cb;
    const int ccb = (ncb > 3) ? 3 : ncb;
    const int boundary = (de == 8) && (cb < 3);
    const char* gcur = gw3b + ((((size_t)de * 2 + py) * 4 + cb) << 15);
    const char* gnxt = gw3b + ((((size_t)nde * 2 + py) * 4 + ccb) << 15);

    bf16x8 bv[4];

    // ---- phase 0 (k8=0) ----
    LOAD_AF_G(afB, gcur, 1);  // k1 of this step: issue ~1 phase before use
    READ_BV(bv, 0);
    MFMA32(afA, bv);

    // ---- phase 1 (k8=1) ----
    LOAD_AF_G(afA, gnxt, 0);  // k0 of next step: ~1 phase of cover
    READ_BV(bv, 1);
    MFMA32(afB, bv);

    if (boundary) {
      __syncthreads();     // all waves done reading xt (phase-1 bv reads complete)
      STAGE_X(cb + 1);
      __syncthreads();     // drain staging (vmcnt 0) + fence for all waves
    }

    d = (nde == 0) ? 0 : ((e == 2) ? d + 1 : d);
    e = (nde == 0) ? 0 : ((e == 2) ? 0 : e + 1);
    de = nde; cb = ncb;
  }
#undef STAGE_X
#undef LOAD_AF_G
#undef READ_BV
#undef MFMA32

  const float kSqrt2 = 1.41421356237309515f;
  const int oh = 2 * (m0 + wn) + py;
#pragma unroll
  for (int i = 0; i < 8; ++i) {
    const int row0 = mb * 128 + i * 16 + l4 * 4;  // even
    const int co0 = row0 >> 1;                    // r=0,1 -> co0 (px=0,1); r=2,3 -> co0+1
    const float bs0 = bias[co0], bs1 = bias[co0 + 1];
#pragma unroll
    for (int j = 0; j < 4; ++j) {
      const int n = j * 16 + l15;
      float v[4];
#pragma unroll
      for (int r = 0; r < 4; ++r) {
        float vv = acc[i][j][r] + ((r < 2) ? bs0 : bs1);
        vv = (vv < 0.f ? 0.01f * vv : vv) * kSqrt2;
        v[r] = fminf(fmaxf(vv, -256.f), 265.f);
      }
      float2* p0 = (float2*)&out[(((size_t)b * COUT + co0) * 128 + oh) * 128 + 2 * n];
      float2* p1 = (float2*)&out[(((size_t)b * COUT + co0 + 1) * 128 + oh) * 128 + 2 * n];
      *p0 = make_float2(v[0], v[1]);
      *p1 = make_float2(v[2], v[3]);
    }
  }
}

extern "C" void kernel_launch(void* const* d_in, const int* in_sizes, int n_in,
                              void* d_out, int out_size, void* d_ws, size_t ws_size,
                              hipStream_t stream) {
  const float* x = (const float*)d_in[0];
  const float* w = (const float*)d_in[1];
  const float* bias = (const float*)d_in[2];
  const float* f = (const float*)d_in[3];
  float* out = (float*)d_out;

  unsigned short* xb2 = (unsigned short*)d_ws;
  unsigned short* gw3 = (unsigned short*)((char*)d_ws + XB2_BYTES);

  hipLaunchKernelGGL(prep_all, dim3(900), dim3(256), 0, stream, x, w, f, xb2, gw3);
  hipLaunchKernelGGL(conv_main, dim3(512), dim3(256), 0, stream, xb2, gw3, bias, out);
}

// Round 15
// 80.037 us; speedup vs baseline: 1.9146x; 1.9146x over previous
//
#include <hip/hip_runtime.h>
#include <stdint.h>

#define CIN 256
#define COUT 128
#define BATCH 8
#define HH 64
#define WW 64
#define XROW 66

// xb2: padded bf16 input, [B][66 rows][66 cols][4 cb][8 slot][8 ch], slot pre-swizzled by (col&7)
#define XB2_BYTES ((size_t)BATCH * XROW * XROW * CIN * 2)
// gw3: fused weights, UNSWIZZLED: [9 taps][2 py][4 cb][256 row=co*2+px][8 g][8 ch]
#define GW3_BYTES ((size_t)9 * 2 * 4 * 256 * 64 * 2)

typedef __bf16 bf16x8 __attribute__((ext_vector_type(8)));
typedef float f32x4 __attribute__((ext_vector_type(4)));

__device__ __forceinline__ unsigned short f2bf(float f) {
  unsigned int u = __float_as_uint(f);
  u += 0x7fffu + ((u >> 16) & 1u);
  return (unsigned short)(u >> 16);
}

__device__ __forceinline__ void gload_lds16(const void* g, void* l) {
  __builtin_amdgcn_global_load_lds(
      (__attribute__((address_space(1))) void*)(uintptr_t)g,
      (__attribute__((address_space(3))) void*)l, 16, 0, 0);
}

// ---------------- fused prep: prep_x (512 blk) + prep_w (128 blk) + border (260 blk) ----------------
__global__ __launch_bounds__(256) void prep_all(const float* __restrict__ x,
                                                const float* __restrict__ w,
                                                const float* __restrict__ f,
                                                unsigned short* __restrict__ xb2,
                                                unsigned short* __restrict__ gw3) {
  __shared__ __align__(16) unsigned short lds[64][264];  // prep_x staging; fs aliases it
  const int blk = blockIdx.x;
  const int t = threadIdx.x;

  if (blk < 512) {
    // ---- prep_x: x -> padded channel-last swizzled bf16 (interior) ----
    int b = blk >> 6, iy = blk & 63;
    int cq = t >> 6, ix = t & 63;
    for (int ci = 0; ci < 64; ++ci) {
      int c = ci * 4 + cq;
      float v = x[(((size_t)b * CIN + c) * HH + iy) * WW + ix];
      lds[ix][c] = f2bf(v);
    }
    __syncthreads();
    for (int it = 0; it < 8; ++it) {
      int u = it * 256 + t;  // 2048 units of 16B: 64 ix * 32 (cb,slot)
      int ixo = u >> 5;
      int q = u & 31, cb = q >> 3, slot = q & 7;
      int col = ixo + 1;  // padded col
      int c0 = cb * 64 + 8 * (slot ^ (col & 7));
      uint4 val = *reinterpret_cast<const uint4*>(&lds[ixo][c0]);
      size_t o = ((((size_t)(b * XROW + (iy + 1)) * XROW + col) * 4 + cb) * 8 + slot) * 8;
      *reinterpret_cast<uint4*>(&xb2[o]) = val;
    }
  } else if (blk < 640) {
    // ---- prep_w: fuse He-scale * conv3x3 (x) FIR; stored UNSWIZZLED [row][g][8ch] ----
    float* fs = (float*)lds;
    int co = blk - 512;
    int c = t;
    if (c < 16) fs[c] = f[c];
    __syncthreads();
    float wl[3][3];
    const float he = 1.0f / 48.0f;  // 1/sqrt(256*9)
#pragma unroll
    for (int dy = 0; dy < 3; ++dy)
#pragma unroll
      for (int dx = 0; dx < 3; ++dx)
        wl[dy][dx] = w[((size_t)(co * CIN + c) * 3 + dy) * 3 + dx] * he;
    int cb = c >> 6, cl = c & 63;
    int g = cl >> 3;
    int ce = cl & 7;
    for (int d = 0; d < 3; ++d)
      for (int e = 0; e < 3; ++e)
        for (int py = 0; py < 2; ++py)
          for (int px = 0; px < 2; ++px) {
            int ty = 2 * d + 1 - py, tx = 2 * e + 1 - px;  // taps of 6x6 composite g
            float acc = 0.f;
            for (int dy = 0; dy < 3; ++dy) {
              int a = ty - dy;
              if (a < 0 || a > 3) continue;
              for (int dx = 0; dx < 3; ++dx) {
                int bb = tx - dx;
                if (bb < 0 || bb > 3) continue;
                acc += wl[dy][dx] * fs[a * 4 + bb];
              }
            }
            int row = co * 2 + px;
            size_t o =
                ((((size_t)(d * 3 + e) * 2 + py) * 4 + cb) * 256 + row) * 64 + g * 8 + ce;
            gw3[o] = f2bf(acc);
          }
  } else {
    // ---- border zeroing ----
    int u = (blk - 640) * 256 + t;
    if (u >= 66560) return;
    int b = u / 8320, v = u - b * 8320;
    int row, col, cs;
    if (v < 4224) {
      int rr = v / 2112;
      int rem = v - rr * 2112;
      row = rr * 65; col = rem >> 5; cs = rem & 31;
    } else {
      int v2 = v - 4224;
      row = 1 + (v2 >> 6);
      int rem = v2 & 63;
      col = (rem >> 5) * 65; cs = rem & 31;
    }
    size_t o = (((size_t)(b * XROW + row) * XROW + col) * 32 + cs) * 8;
    *reinterpret_cast<uint4*>(&xb2[o]) = make_uint4(0, 0, 0, 0);
  }
}

// ---------------- main: implicit-GEMM polyphase conv ----------------
// R13 structure (BM=128/BN=256, 4 waves 1Mx4N, wave tile 128x64, A in two 8KB LDS
// k8-halves restaged in place, X 50.7KB single-buffered, 2 blocks/CU) with the
// per-cluster convoy removed: NO manual lgkmcnt(0)/sched_barrier before MFMA —
// the compiler inserts COUNTED lgkm waits (m97). Operand fragments double-buffered:
// each cluster's ds_reads are issued one full cluster (~620cy) ahead, so its wait
// is ~0-stall. Full lgkmcnt(0) only right before the two barriers (read-retirement
// required for the in-place A restage).
__global__ __launch_bounds__(256, 2) void conv_main(
    const unsigned short* __restrict__ xb2,
    const unsigned short* __restrict__ gw3,
    const float* __restrict__ bias,
    float* __restrict__ out) {
  __shared__ __align__(16) unsigned char smem[8192 + 8192 + 50688];
  unsigned short* ah0 = (unsigned short*)smem;            // A k8=0 half: [128 row][4 qp][16B]
  unsigned short* ah1 = (unsigned short*)(smem + 8192);   // A k8=1 half
  unsigned short* xt = (unsigned short*)(smem + 16384);   // X: [6 xrow][66 col][8 slot][16B]

  const int bid = blockIdx.x;
  const int b = bid & 7;              // XCD b-affinity
  const int mg = (bid >> 3) & 15;
  const int mb = (bid >> 7) & 1;      // weight-row half
  const int py = (bid >> 8) & 1;
  const int m0 = mg * 4;              // 4 output sub-rows per block

  const int t = threadIdx.x;
  const int lane = t & 63;
  const int wn = t >> 6;              // wave 0..3 = output sub-row
  const int l15 = lane & 15, l4 = lane >> 4;
  const int qpc = l4 ^ ((l15 >> 1) & 3);  // af physical slot (lane-constant)

  f32x4 acc[8][4] = {};
  bf16x8 af0[8], af1[8], bv0[4], bv1[4];  // cluster-level operand double-buffer

  const char* xbase = (const char*)xb2 + (size_t)((b * XROW + m0) * (XROW * 32)) * 16;
  const char* gw3b = (const char*)gw3 + mb * 16384;

  // stage one 8KB k8-half of A for tap (de,cb): 512 units, 2 gloads/thread.
#define STAGE_AH(DSTH, K8, de_, cb_)                                                   \
  do {                                                                                 \
    const char* g_ = gw3b + ((((size_t)(de_)*2 + py) * 4 + (cb_)) << 15);              \
    _Pragma("unroll") for (int it = 0; it < 2; ++it) {                                 \
      int u = it * 256 + t;                                                            \
      int lrow = u >> 2, qp = u & 3;                                                   \
      int gg = (K8)*4 + (qp ^ ((lrow >> 1) & 3));                                      \
      gload_lds16(g_ + lrow * 128 + gg * 16, (char*)(DSTH) + u * 16);                  \
    }                                                                                  \
  } while (0)

  // X tile per cb: 6 rows x 66 cols x 8 slots = 3168 16B units; 13 iters of 256
#define STAGE_X(cb_)                                                          \
  do {                                                                        \
    int rr_ = 0, rem_ = t;                                                    \
    for (int it = 0; it < 13; ++it) {                                         \
      int u = it * 256 + t;                                                   \
      if (u < 3168) {                                                         \
        int col = rem_ >> 3, slot = rem_ & 7;                                 \
        size_t go = (size_t)(rr_ * XROW + col) * 32 + (cb_)*8 + slot;         \
        gload_lds16(xbase + go * 16, (char*)xt + (size_t)u * 16);             \
      }                                                                       \
      rem_ += 256;                                                            \
      if (rem_ >= 528) { rem_ -= 528; ++rr_; }                                \
    }                                                                         \
  } while (0)

#define BAR()                        \
  do {                               \
    asm volatile("" ::: "memory");   \
    __builtin_amdgcn_s_barrier();    \
    asm volatile("" ::: "memory");   \
  } while (0)

#define READ_AF(AF, AH)                                                                \
  do {                                                                                 \
    _Pragma("unroll") for (int i = 0; i < 8; ++i)                                      \
        (AF)[i] = *(const bf16x8*)((const char*)(AH) + i * 1024 + l15 * 64 + qpc * 16);\
  } while (0)

#define READ_BV(BV, K8, D_, E_)                                                        \
  do {                                                                                 \
    const int xr_ = wn + (D_);                                                         \
    _Pragma("unroll") for (int j = 0; j < 4; ++j) {                                    \
      int col = j * 16 + l15 + (E_);                                                   \
      int slot = ((K8)*4 + l4) ^ (col & 7);                                            \
      (BV)[j] = *(const bf16x8*)(xt + ((size_t)xr_ * 66 + col) * 64 + slot * 8);       \
    }                                                                                  \
  } while (0)

  // NO manual waits here — compiler inserts counted lgkm waits for operands
#define MFMA32(AF, BV)                                                                   \
  do {                                                                                   \
    __builtin_amdgcn_s_setprio(1);                                                       \
    _Pragma("unroll") for (int i = 0; i < 8; ++i)                                        \
      _Pragma("unroll") for (int j = 0; j < 4; ++j)                                      \
        acc[i][j] =                                                                      \
            __builtin_amdgcn_mfma_f32_16x16x32_bf16((AF)[i], (BV)[j], acc[i][j], 0, 0, 0); \
    __builtin_amdgcn_s_setprio(0);                                                       \
  } while (0)

  // prologue: A halves (s=0) + X(cb=0); drain; then cluster-0 reads
  STAGE_AH(ah0, 0, 0, 0);
  STAGE_AH(ah1, 1, 0, 0);
  STAGE_X(0);
  asm volatile("s_waitcnt vmcnt(0)" ::: "memory");
  BAR();
  READ_AF(af0, ah0);
  READ_BV(bv0, 0, 0, 0);

  int cb = 0, de = 0, d = 0, e = 0;
  for (int s = 0; s < 36; ++s) {
    const int notlast = (s < 35);
    const int nde = (de == 8) ? 0 : de + 1;
    const int ncb = (de == 8) ? cb + 1 : cb;
    const int ccb = (ncb > 3) ? 3 : ncb;
    const int boundary = (de == 8) && (cb < 3);
    const int nd = nde / 3, ne = nde - nd * 3;

    // ---- phase 0 (cluster af0/bv0) ----
    // af0 reads retired by all waves before ah0 overwrite; ah1(s) stage landed.
    asm volatile("s_waitcnt vmcnt(0) lgkmcnt(0)" ::: "memory");
    BAR();
    if (notlast) STAGE_AH(ah0, 0, nde, ccb);
    READ_AF(af1, ah1);        // cluster-1 reads issued BEFORE cluster-0 MFMA
    READ_BV(bv1, 1, d, e);
    MFMA32(af0, bv0);

    // ---- phase 1 (cluster af1/bv1) ----
    asm volatile("s_waitcnt vmcnt(0) lgkmcnt(0)" ::: "memory");
    BAR();
    if (notlast) STAGE_AH(ah1, 1, nde, ccb);
    if (boundary) {
      STAGE_X(cb + 1);
      asm volatile("s_waitcnt vmcnt(0)" ::: "memory");
      BAR();
    }
    if (notlast) {
      READ_AF(af0, ah0);      // next-step cluster-0 reads (ah0 already restaged)
      READ_BV(bv0, 0, nd, ne);
    }
    MFMA32(af1, bv1);

    d = nd; e = ne; de = nde; cb = ncb;
  }
#undef STAGE_AH
#undef STAGE_X
#undef READ_AF
#undef READ_BV
#undef MFMA32

  const float kSqrt2 = 1.41421356237309515f;
  const int oh = 2 * (m0 + wn) + py;
#pragma unroll
  for (int i = 0; i < 8; ++i) {
    const int row0 = mb * 128 + i * 16 + l4 * 4;  // even
    const int co0 = row0 >> 1;                    // r=0,1 -> co0 (px=0,1); r=2,3 -> co0+1
    const float bs0 = bias[co0], bs1 = bias[co0 + 1];
#pragma unroll
    for (int j = 0; j < 4; ++j) {
      const int n = j * 16 + l15;
      float v[4];
#pragma unroll
      for (int r = 0; r < 4; ++r) {
        float vv = acc[i][j][r] + ((r < 2) ? bs0 : bs1);
        vv = (vv < 0.f ? 0.01f * vv : vv) * kSqrt2;
        v[r] = fminf(fmaxf(vv, -256.f), 265.f);
      }
      float2* p0 = (float2*)&out[(((size_t)b * COUT + co0) * 128 + oh) * 128 + 2 * n];
      float2* p1 = (float2*)&out[(((size_t)b * COUT + co0 + 1) * 128 + oh) * 128 + 2 * n];
      *p0 = make_float2(v[0], v[1]);
      *p1 = make_float2(v[2], v[3]);
    }
  }
}

extern "C" void kernel_launch(void* const* d_in, const int* in_sizes, int n_in,
                              void* d_out, int out_size, void* d_ws, size_t ws_size,
                              hipStream_t stream) {
  const float* x = (const float*)d_in[0];
  const float* w = (const float*)d_in[1];
  const float* bias = (const float*)d_in[2];
  const float* f = (const float*)d_in[3];
  float* out = (float*)d_out;

  unsigned short* xb2 = (unsigned short*)d_ws;
  unsigned short* gw3 = (unsigned short*)((char*)d_ws + XB2_BYTES);

  hipLaunchKernelGGL(prep_all, dim3(900), dim3(256), 0, stream, x, w, f, xb2, gw3);
  hipLaunchKernelGGL(conv_main, dim3(512), dim3(256), 0, stream, xb2, gw3, bias, out);
}

// Round 16
// 77.084 us; speedup vs baseline: 1.9879x; 1.0383x over previous
//
#include <hip/hip_runtime.h>
#include <stdint.h>

#define CIN 256
#define COUT 128
#define BATCH 8
#define HH 64
#define WW 64
#define XROW 66

// xb2: padded bf16 input, [B][66 rows][66 cols][4 cb][8 slot][8 ch], slot pre-swizzled by (col&7)
#define XB2_BYTES ((size_t)BATCH * XROW * XROW * CIN * 2)
// gw3: fused weights, UNSWIZZLED: [9 taps][2 py][4 cb][256 row=co*2+px][8 g][8 ch]
#define GW3_BYTES ((size_t)9 * 2 * 4 * 256 * 64 * 2)

typedef __bf16 bf16x8 __attribute__((ext_vector_type(8)));
typedef float f32x4 __attribute__((ext_vector_type(4)));

__device__ __forceinline__ unsigned short f2bf(float f) {
  unsigned int u = __float_as_uint(f);
  u += 0x7fffu + ((u >> 16) & 1u);
  return (unsigned short)(u >> 16);
}

__device__ __forceinline__ void gload_lds16(const void* g, void* l) {
  __builtin_amdgcn_global_load_lds(
      (__attribute__((address_space(1))) void*)(uintptr_t)g,
      (__attribute__((address_space(3))) void*)l, 16, 0, 0);
}

// ---------------- fused prep: prep_x (512 blk) + prep_w (128 blk) + border (260 blk) ----------------
__global__ __launch_bounds__(256) void prep_all(const float* __restrict__ x,
                                                const float* __restrict__ w,
                                                const float* __restrict__ f,
                                                unsigned short* __restrict__ xb2,
                                                unsigned short* __restrict__ gw3) {
  __shared__ __align__(16) unsigned short lds[64][264];  // prep_x staging; fs aliases it
  const int blk = blockIdx.x;
  const int t = threadIdx.x;

  if (blk < 512) {
    // ---- prep_x: x -> padded channel-last swizzled bf16 (interior) ----
    int b = blk >> 6, iy = blk & 63;
    int cq = t >> 6, ix = t & 63;
    for (int ci = 0; ci < 64; ++ci) {
      int c = ci * 4 + cq;
      float v = x[(((size_t)b * CIN + c) * HH + iy) * WW + ix];
      lds[ix][c] = f2bf(v);
    }
    __syncthreads();
    for (int it = 0; it < 8; ++it) {
      int u = it * 256 + t;  // 2048 units of 16B: 64 ix * 32 (cb,slot)
      int ixo = u >> 5;
      int q = u & 31, cb = q >> 3, slot = q & 7;
      int col = ixo + 1;  // padded col
      int c0 = cb * 64 + 8 * (slot ^ (col & 7));
      uint4 val = *reinterpret_cast<const uint4*>(&lds[ixo][c0]);
      size_t o = ((((size_t)(b * XROW + (iy + 1)) * XROW + col) * 4 + cb) * 8 + slot) * 8;
      *reinterpret_cast<uint4*>(&xb2[o]) = val;
    }
  } else if (blk < 640) {
    // ---- prep_w: fuse He-scale * conv3x3 (x) FIR; stored UNSWIZZLED [row][g][8ch] ----
    float* fs = (float*)lds;
    int co = blk - 512;
    int c = t;
    if (c < 16) fs[c] = f[c];
    __syncthreads();
    float wl[3][3];
    const float he = 1.0f / 48.0f;  // 1/sqrt(256*9)
#pragma unroll
    for (int dy = 0; dy < 3; ++dy)
#pragma unroll
      for (int dx = 0; dx < 3; ++dx)
        wl[dy][dx] = w[((size_t)(co * CIN + c) * 3 + dy) * 3 + dx] * he;
    int cb = c >> 6, cl = c & 63;
    int g = cl >> 3;
    int ce = cl & 7;
    for (int d = 0; d < 3; ++d)
      for (int e = 0; e < 3; ++e)
        for (int py = 0; py < 2; ++py)
          for (int px = 0; px < 2; ++px) {
            int ty = 2 * d + 1 - py, tx = 2 * e + 1 - px;  // taps of 6x6 composite g
            float acc = 0.f;
            for (int dy = 0; dy < 3; ++dy) {
              int a = ty - dy;
              if (a < 0 || a > 3) continue;
              for (int dx = 0; dx < 3; ++dx) {
                int bb = tx - dx;
                if (bb < 0 || bb > 3) continue;
                acc += wl[dy][dx] * fs[a * 4 + bb];
              }
            }
            int row = co * 2 + px;
            size_t o =
                ((((size_t)(d * 3 + e) * 2 + py) * 4 + cb) * 256 + row) * 64 + g * 8 + ce;
            gw3[o] = f2bf(acc);
          }
  } else {
    // ---- border zeroing ----
    int u = (blk - 640) * 256 + t;
    if (u >= 66560) return;
    int b = u / 8320, v = u - b * 8320;
    int row, col, cs;
    if (v < 4224) {
      int rr = v / 2112;
      int rem = v - rr * 2112;
      row = rr * 65; col = rem >> 5; cs = rem & 31;
    } else {
      int v2 = v - 4224;
      row = 1 + (v2 >> 6);
      int rem = v2 & 63;
      col = (rem >> 5) * 65; cs = rem & 31;
    }
    size_t o = (((size_t)(b * XROW + row) * XROW + col) * 32 + cs) * 8;
    *reinterpret_cast<uint4*>(&xb2[o]) = make_uint4(0, 0, 0, 0);
  }
}

// ---------------- main: implicit-GEMM polyphase conv ----------------
// R13 structure EXACTLY (BM=128/BN=256, 4 waves 1Mx4N, wave tile 128x64, A in two
// 8KB LDS k8-halves restaged in place, X 50.7KB single-buffered, 2 blocks/CU,
// ~120 VGPR — R15's read-ahead spilled at the 128 cap and regressed), with one
// change: NO manual lgkmcnt(0)/sched_barrier(0) before the MFMA clusters. The
// compiler emits COUNTED lgkm waits per operand (m97 evidence), so the first MFMA
// waits only for its own fragments and trailing ds_reads retire under compute
// (vs R13's force-drain of all 12 reads + order pin — m141's anti-pattern).
__global__ __launch_bounds__(256, 2) void conv_main(
    const unsigned short* __restrict__ xb2,
    const unsigned short* __restrict__ gw3,
    const float* __restrict__ bias,
    float* __restrict__ out) {
  __shared__ __align__(16) unsigned char smem[8192 + 8192 + 50688];
  unsigned short* ah0 = (unsigned short*)smem;            // A k8=0 half: [128 row][4 qp][16B]
  unsigned short* ah1 = (unsigned short*)(smem + 8192);   // A k8=1 half
  unsigned short* xt = (unsigned short*)(smem + 16384);   // X: [6 xrow][66 col][8 slot][16B]

  const int bid = blockIdx.x;
  const int b = bid & 7;              // XCD b-affinity
  const int mg = (bid >> 3) & 15;
  const int mb = (bid >> 7) & 1;      // weight-row half
  const int py = (bid >> 8) & 1;
  const int m0 = mg * 4;              // 4 output sub-rows per block

  const int t = threadIdx.x;
  const int lane = t & 63;
  const int wn = t >> 6;              // wave 0..3 = output sub-row
  const int l15 = lane & 15, l4 = lane >> 4;
  const int qpc = l4 ^ ((l15 >> 1) & 3);  // af physical slot (lane-constant)

  f32x4 acc[8][4] = {};

  const char* xbase = (const char*)xb2 + (size_t)((b * XROW + m0) * (XROW * 32)) * 16;
  const char* gw3b = (const char*)gw3 + mb * 16384;

  // stage one 8KB k8-half of A for tap (de,cb): 512 units, 2 gloads/thread.
#define STAGE_AH(DSTH, K8, de_, cb_)                                                   \
  do {                                                                                 \
    const char* g_ = gw3b + ((((size_t)(de_)*2 + py) * 4 + (cb_)) << 15);              \
    _Pragma("unroll") for (int it = 0; it < 2; ++it) {                                 \
      int u = it * 256 + t;                                                            \
      int lrow = u >> 2, qp = u & 3;                                                   \
      int gg = (K8)*4 + (qp ^ ((lrow >> 1) & 3));                                      \
      gload_lds16(g_ + lrow * 128 + gg * 16, (char*)(DSTH) + u * 16);                  \
    }                                                                                  \
  } while (0)

  // X tile per cb: 6 rows x 66 cols x 8 slots = 3168 16B units; 13 iters of 256
#define STAGE_X(cb_)                                                          \
  do {                                                                        \
    int rr_ = 0, rem_ = t;                                                    \
    for (int it = 0; it < 13; ++it) {                                         \
      int u = it * 256 + t;                                                   \
      if (u < 3168) {                                                         \
        int col = rem_ >> 3, slot = rem_ & 7;                                 \
        size_t go = (size_t)(rr_ * XROW + col) * 32 + (cb_)*8 + slot;         \
        gload_lds16(xbase + go * 16, (char*)xt + (size_t)u * 16);             \
      }                                                                       \
      rem_ += 256;                                                            \
      if (rem_ >= 528) { rem_ -= 528; ++rr_; }                                \
    }                                                                         \
  } while (0)

#define BAR()                        \
  do {                               \
    asm volatile("" ::: "memory");   \
    __builtin_amdgcn_s_barrier();    \
    asm volatile("" ::: "memory");   \
  } while (0)

#define READ_AF(AF, AH)                                                                \
  do {                                                                                 \
    _Pragma("unroll") for (int i = 0; i < 8; ++i)                                      \
        (AF)[i] = *(const bf16x8*)((const char*)(AH) + i * 1024 + l15 * 64 + qpc * 16);\
  } while (0)

#define READ_BV(BV, K8)                                                                \
  do {                                                                                 \
    _Pragma("unroll") for (int j = 0; j < 4; ++j) {                                    \
      int col = j * 16 + l15 + e;                                                      \
      int slot = ((K8)*4 + l4) ^ (col & 7);                                            \
      (BV)[j] = *(const bf16x8*)(xt + ((size_t)xr * 66 + col) * 64 + slot * 8);        \
    }                                                                                  \
  } while (0)

  // NO manual waits / order pins — compiler inserts counted lgkm waits per operand
#define MFMA32(AF, BV)                                                                   \
  do {                                                                                   \
    __builtin_amdgcn_s_setprio(1);                                                       \
    _Pragma("unroll") for (int i = 0; i < 8; ++i)                                        \
      _Pragma("unroll") for (int j = 0; j < 4; ++j)                                      \
        acc[i][j] =                                                                      \
            __builtin_amdgcn_mfma_f32_16x16x32_bf16((AF)[i], (BV)[j], acc[i][j], 0, 0, 0); \
    __builtin_amdgcn_s_setprio(0);                                                       \
  } while (0)

  // prologue: A halves (s=0) + X(cb=0); full drain; barrier
  STAGE_AH(ah0, 0, 0, 0);
  STAGE_AH(ah1, 1, 0, 0);
  STAGE_X(0);
  asm volatile("s_waitcnt vmcnt(0)" ::: "memory");
  BAR();

  int cb = 0, de = 0, d = 0, e = 0;
  for (int s = 0; s < 36; ++s) {
    const int xr = wn + d;
    const int notlast = (s < 35);
    const int nde = (de == 8) ? 0 : de + 1;
    const int ncb = (de == 8) ? cb + 1 : cb;
    const int boundary = (de == 8) && (cb < 3);

    bf16x8 af[8], bv[4];

    // ---- phase 0 (k8=0) ----
    READ_AF(af, ah0);
    READ_BV(bv, 0);
    asm volatile("s_waitcnt vmcnt(0)" ::: "memory");  // drain prev step's ah1 stage
    BAR();                                            // #1: ah0 reads done by all waves
    if (notlast) STAGE_AH(ah0, 0, nde, ncb);          // restage ah0 in place
    MFMA32(af, bv);

    // ---- phase 1 (k8=1) ----
    READ_AF(af, ah1);
    READ_BV(bv, 1);
    asm volatile("s_waitcnt vmcnt(0)" ::: "memory");  // drain my ah0 stage (issued ~1 phase ago)
    BAR();                                            // #2: ah1 + xt reads done by all waves
    if (boundary) STAGE_X(cb + 1);
    if (notlast) STAGE_AH(ah1, 1, nde, ncb);          // restage ah1 in place
    if (boundary) {
      // X' must be visible to next step's phase-0 bv reads: drain all but ah1's 2, fence
      asm volatile("s_waitcnt vmcnt(2)" ::: "memory");
      BAR();
    }
    MFMA32(af, bv);

    d = (nde == 0) ? 0 : ((e == 2) ? d + 1 : d);
    e = (nde == 0) ? 0 : ((e == 2) ? 0 : e + 1);
    de = nde; cb = ncb;
  }
#undef STAGE_AH
#undef STAGE_X
#undef READ_AF
#undef READ_BV
#undef MFMA32

  const float kSqrt2 = 1.41421356237309515f;
  const int oh = 2 * (m0 + wn) + py;
#pragma unroll
  for (int i = 0; i < 8; ++i) {
    const int row0 = mb * 128 + i * 16 + l4 * 4;  // even
    const int co0 = row0 >> 1;                    // r=0,1 -> co0 (px=0,1); r=2,3 -> co0+1
    const float bs0 = bias[co0], bs1 = bias[co0 + 1];
#pragma unroll
    for (int j = 0; j < 4; ++j) {
      const int n = j * 16 + l15;
      float v[4];
#pragma unroll
      for (int r = 0; r < 4; ++r) {
        float vv = acc[i][j][r] + ((r < 2) ? bs0 : bs1);
        vv = (vv < 0.f ? 0.01f * vv : vv) * kSqrt2;
        v[r] = fminf(fmaxf(vv, -256.f), 265.f);
      }
      float2* p0 = (float2*)&out[(((size_t)b * COUT + co0) * 128 + oh) * 128 + 2 * n];
      float2* p1 = (float2*)&out[(((size_t)b * COUT + co0 + 1) * 128 + oh) * 128 + 2 * n];
      *p0 = make_float2(v[0], v[1]);
      *p1 = make_float2(v[2], v[3]);
    }
  }
}

extern "C" void kernel_launch(void* const* d_in, const int* in_sizes, int n_in,
                              void* d_out, int out_size, void* d_ws, size_t ws_size,
                              hipStream_t stream) {
  const float* x = (const float*)d_in[0];
  const float* w = (const float*)d_in[1];
  const float* bias = (const float*)d_in[2];
  const float* f = (const float*)d_in[3];
  float* out = (float*)d_out;

  unsigned short* xb2 = (unsigned short*)d_ws;
  unsigned short* gw3 = (unsigned short*)((char*)d_ws + XB2_BYTES);

  hipLaunchKernelGGL(prep_all, dim3(900), dim3(256), 0, stream, x, w, f, xb2, gw3);
  hipLaunchKernelGGL(conv_main, dim3(512), dim3(256), 0, stream, xb2, gw3, bias, out);
}

// Round 17
// 76.796 us; speedup vs baseline: 1.9954x; 1.0037x over previous
//
#include <hip/hip_runtime.h>
#include <stdint.h>

#define CIN 256
#define COUT 128
#define BATCH 8
#define HH 64
#define WW 64
#define XROW 66

// xb2: padded bf16 input, [B][66 rows][66 cols][4 cb][8 slot][8 ch], slot pre-swizzled by (col&7)
#define XB2_BYTES ((size_t)BATCH * XROW * XROW * CIN * 2)
// gw3: fused weights, UNSWIZZLED: [9 taps][2 py][4 cb][256 row=co*2+px][8 g][8 ch]
#define GW3_BYTES ((size_t)9 * 2 * 4 * 256 * 64 * 2)

typedef __bf16 bf16x8 __attribute__((ext_vector_type(8)));
typedef float f32x4 __attribute__((ext_vector_type(4)));

__device__ __forceinline__ unsigned short f2bf(float f) {
  unsigned int u = __float_as_uint(f);
  u += 0x7fffu + ((u >> 16) & 1u);
  return (unsigned short)(u >> 16);
}

__device__ __forceinline__ void gload_lds16(const void* g, void* l) {
  __builtin_amdgcn_global_load_lds(
      (__attribute__((address_space(1))) void*)(uintptr_t)g,
      (__attribute__((address_space(3))) void*)l, 16, 0, 0);
}

// ---------------- fused prep: prep_x (512 blk) + prep_w (128 blk) + border (260 blk) ----------------
__global__ __launch_bounds__(256) void prep_all(const float* __restrict__ x,
                                                const float* __restrict__ w,
                                                const float* __restrict__ f,
                                                unsigned short* __restrict__ xb2,
                                                unsigned short* __restrict__ gw3) {
  __shared__ __align__(16) unsigned short lds[64][264];  // prep_x staging; fs aliases it
  const int blk = blockIdx.x;
  const int t = threadIdx.x;

  if (blk < 512) {
    // ---- prep_x: x -> padded channel-last swizzled bf16 (interior) ----
    int b = blk >> 6, iy = blk & 63;
    int cq = t >> 6, ix = t & 63;
    for (int ci = 0; ci < 64; ++ci) {
      int c = ci * 4 + cq;
      float v = x[(((size_t)b * CIN + c) * HH + iy) * WW + ix];
      lds[ix][c] = f2bf(v);
    }
    __syncthreads();
    for (int it = 0; it < 8; ++it) {
      int u = it * 256 + t;  // 2048 units of 16B: 64 ix * 32 (cb,slot)
      int ixo = u >> 5;
      int q = u & 31, cb = q >> 3, slot = q & 7;
      int col = ixo + 1;  // padded col
      int c0 = cb * 64 + 8 * (slot ^ (col & 7));
      uint4 val = *reinterpret_cast<const uint4*>(&lds[ixo][c0]);
      size_t o = ((((size_t)(b * XROW + (iy + 1)) * XROW + col) * 4 + cb) * 8 + slot) * 8;
      *reinterpret_cast<uint4*>(&xb2[o]) = val;
    }
  } else if (blk < 640) {
    // ---- prep_w: fuse He-scale * conv3x3 (x) FIR; stored UNSWIZZLED [row][g][8ch] ----
    float* fs = (float*)lds;
    int co = blk - 512;
    int c = t;
    if (c < 16) fs[c] = f[c];
    __syncthreads();
    float wl[3][3];
    const float he = 1.0f / 48.0f;  // 1/sqrt(256*9)
#pragma unroll
    for (int dy = 0; dy < 3; ++dy)
#pragma unroll
      for (int dx = 0; dx < 3; ++dx)
        wl[dy][dx] = w[((size_t)(co * CIN + c) * 3 + dy) * 3 + dx] * he;
    int cb = c >> 6, cl = c & 63;
    int g = cl >> 3;
    int ce = cl & 7;
    for (int d = 0; d < 3; ++d)
      for (int e = 0; e < 3; ++e)
        for (int py = 0; py < 2; ++py)
          for (int px = 0; px < 2; ++px) {
            int ty = 2 * d + 1 - py, tx = 2 * e + 1 - px;  // taps of 6x6 composite g
            float acc = 0.f;
            for (int dy = 0; dy < 3; ++dy) {
              int a = ty - dy;
              if (a < 0 || a > 3) continue;
              for (int dx = 0; dx < 3; ++dx) {
                int bb = tx - dx;
                if (bb < 0 || bb > 3) continue;
                acc += wl[dy][dx] * fs[a * 4 + bb];
              }
            }
            int row = co * 2 + px;
            size_t o =
                ((((size_t)(d * 3 + e) * 2 + py) * 4 + cb) * 256 + row) * 64 + g * 8 + ce;
            gw3[o] = f2bf(acc);
          }
  } else {
    // ---- border zeroing ----
    int u = (blk - 640) * 256 + t;
    if (u >= 66560) return;
    int b = u / 8320, v = u - b * 8320;
    int row, col, cs;
    if (v < 4224) {
      int rr = v / 2112;
      int rem = v - rr * 2112;
      row = rr * 65; col = rem >> 5; cs = rem & 31;
    } else {
      int v2 = v - 4224;
      row = 1 + (v2 >> 6);
      int rem = v2 & 63;
      col = (rem >> 5) * 65; cs = rem & 31;
    }
    size_t o = (((size_t)(b * XROW + row) * XROW + col) * 32 + cs) * 8;
    *reinterpret_cast<uint4*>(&xb2[o]) = make_uint4(0, 0, 0, 0);
  }
}

// ---------------- main: implicit-GEMM polyphase conv ----------------
// R16 structure EXACTLY (BM=128/BN=256, 4 waves 1Mx4N, wave tile 128x64, A in two
// 8KB LDS k8-halves restaged in place, X 50.7KB single-buffered, 2 blocks/CU,
// 120 VGPR, compiler-counted lgkm waits) + ANTI-PHASE STAGGER: same-CU block pairs
// are (bid, bid+256) [8-XCD round-robin], differing exactly in py. The py=1 block
// sleeps ~2300cy (half a step) at entry so its MFMA clusters land in its partner's
// read/barrier windows — turning the measured ~50% cross-block overlap (identical
// periodic machines launched in-phase) toward full anti-phase hiding.
__global__ __launch_bounds__(256, 2) void conv_main(
    const unsigned short* __restrict__ xb2,
    const unsigned short* __restrict__ gw3,
    const float* __restrict__ bias,
    float* __restrict__ out) {
  __shared__ __align__(16) unsigned char smem[8192 + 8192 + 50688];
  unsigned short* ah0 = (unsigned short*)smem;            // A k8=0 half: [128 row][4 qp][16B]
  unsigned short* ah1 = (unsigned short*)(smem + 8192);   // A k8=1 half
  unsigned short* xt = (unsigned short*)(smem + 16384);   // X: [6 xrow][66 col][8 slot][16B]

  const int bid = blockIdx.x;
  const int b = bid & 7;              // XCD b-affinity
  const int mg = (bid >> 3) & 15;
  const int mb = (bid >> 7) & 1;      // weight-row half
  const int py = (bid >> 8) & 1;
  const int m0 = mg * 4;              // 4 output sub-rows per block

  // anti-phase stagger: py selects one block of each same-CU pair
  if (py) {
    __builtin_amdgcn_s_sleep(9);  // ~576 cyc
    __builtin_amdgcn_s_sleep(9);
    __builtin_amdgcn_s_sleep(9);
    __builtin_amdgcn_s_sleep(9);  // total ~2300 cyc ~= half a K-step
  }

  const int t = threadIdx.x;
  const int lane = t & 63;
  const int wn = t >> 6;              // wave 0..3 = output sub-row
  const int l15 = lane & 15, l4 = lane >> 4;
  const int qpc = l4 ^ ((l15 >> 1) & 3);  // af physical slot (lane-constant)

  f32x4 acc[8][4] = {};

  const char* xbase = (const char*)xb2 + (size_t)((b * XROW + m0) * (XROW * 32)) * 16;
  const char* gw3b = (const char*)gw3 + mb * 16384;

  // stage one 8KB k8-half of A for tap (de,cb): 512 units, 2 gloads/thread.
#define STAGE_AH(DSTH, K8, de_, cb_)                                                   \
  do {                                                                                 \
    const char* g_ = gw3b + ((((size_t)(de_)*2 + py) * 4 + (cb_)) << 15);              \
    _Pragma("unroll") for (int it = 0; it < 2; ++it) {                                 \
      int u = it * 256 + t;                                                            \
      int lrow = u >> 2, qp = u & 3;                                                   \
      int gg = (K8)*4 + (qp ^ ((lrow >> 1) & 3));                                      \
      gload_lds16(g_ + lrow * 128 + gg * 16, (char*)(DSTH) + u * 16);                  \
    }                                                                                  \
  } while (0)

  // X tile per cb: 6 rows x 66 cols x 8 slots = 3168 16B units; 13 iters of 256
#define STAGE_X(cb_)                                                          \
  do {                                                                        \
    int rr_ = 0, rem_ = t;                                                    \
    for (int it = 0; it < 13; ++it) {                                         \
      int u = it * 256 + t;                                                   \
      if (u < 3168) {                                                         \
        int col = rem_ >> 3, slot = rem_ & 7;                                 \
        size_t go = (size_t)(rr_ * XROW + col) * 32 + (cb_)*8 + slot;         \
        gload_lds16(xbase + go * 16, (char*)xt + (size_t)u * 16);             \
      }                                                                       \
      rem_ += 256;                                                            \
      if (rem_ >= 528) { rem_ -= 528; ++rr_; }                                \
    }                                                                         \
  } while (0)

#define BAR()                        \
  do {                               \
    asm volatile("" ::: "memory");   \
    __builtin_amdgcn_s_barrier();    \
    asm volatile("" ::: "memory");   \
  } while (0)

#define READ_AF(AF, AH)                                                                \
  do {                                                                                 \
    _Pragma("unroll") for (int i = 0; i < 8; ++i)                                      \
        (AF)[i] = *(const bf16x8*)((const char*)(AH) + i * 1024 + l15 * 64 + qpc * 16);\
  } while (0)

#define READ_BV(BV, K8)                                                                \
  do {                                                                                 \
    _Pragma("unroll") for (int j = 0; j < 4; ++j) {                                    \
      int col = j * 16 + l15 + e;                                                      \
      int slot = ((K8)*4 + l4) ^ (col & 7);                                            \
      (BV)[j] = *(const bf16x8*)(xt + ((size_t)xr * 66 + col) * 64 + slot * 8);        \
    }                                                                                  \
  } while (0)

  // NO manual waits / order pins — compiler inserts counted lgkm waits per operand
#define MFMA32(AF, BV)                                                                   \
  do {                                                                                   \
    __builtin_amdgcn_s_setprio(1);                                                       \
    _Pragma("unroll") for (int i = 0; i < 8; ++i)                                        \
      _Pragma("unroll") for (int j = 0; j < 4; ++j)                                      \
        acc[i][j] =                                                                      \
            __builtin_amdgcn_mfma_f32_16x16x32_bf16((AF)[i], (BV)[j], acc[i][j], 0, 0, 0); \
    __builtin_amdgcn_s_setprio(0);                                                       \
  } while (0)

  // prologue: A halves (s=0) + X(cb=0); full drain; barrier
  STAGE_AH(ah0, 0, 0, 0);
  STAGE_AH(ah1, 1, 0, 0);
  STAGE_X(0);
  asm volatile("s_waitcnt vmcnt(0)" ::: "memory");
  BAR();

  int cb = 0, de = 0, d = 0, e = 0;
  for (int s = 0; s < 36; ++s) {
    const int xr = wn + d;
    const int notlast = (s < 35);
    const int nde = (de == 8) ? 0 : de + 1;
    const int ncb = (de == 8) ? cb + 1 : cb;
    const int boundary = (de == 8) && (cb < 3);

    bf16x8 af[8], bv[4];

    // ---- phase 0 (k8=0) ----
    READ_AF(af, ah0);
    READ_BV(bv, 0);
    asm volatile("s_waitcnt vmcnt(0)" ::: "memory");  // drain prev step's ah1 stage
    BAR();                                            // #1: ah0 reads done by all waves
    if (notlast) STAGE_AH(ah0, 0, nde, ncb);          // restage ah0 in place
    MFMA32(af, bv);

    // ---- phase 1 (k8=1) ----
    READ_AF(af, ah1);
    READ_BV(bv, 1);
    asm volatile("s_waitcnt vmcnt(0)" ::: "memory");  // drain my ah0 stage (issued ~1 phase ago)
    BAR();                                            // #2: ah1 + xt reads done by all waves
    if (boundary) STAGE_X(cb + 1);
    if (notlast) STAGE_AH(ah1, 1, nde, ncb);          // restage ah1 in place
    if (boundary) {
      // X' must be visible to next step's phase-0 bv reads: drain all but ah1's 2, fence
      asm volatile("s_waitcnt vmcnt(2)" ::: "memory");
      BAR();
    }
    MFMA32(af, bv);

    d = (nde == 0) ? 0 : ((e == 2) ? d + 1 : d);
    e = (nde == 0) ? 0 : ((e == 2) ? 0 : e + 1);
    de = nde; cb = ncb;
  }
#undef STAGE_AH
#undef STAGE_X
#undef READ_AF
#undef READ_BV
#undef MFMA32

  const float kSqrt2 = 1.41421356237309515f;
  const int oh = 2 * (m0 + wn) + py;
#pragma unroll
  for (int i = 0; i < 8; ++i) {
    const int row0 = mb * 128 + i * 16 + l4 * 4;  // even
    const int co0 = row0 >> 1;                    // r=0,1 -> co0 (px=0,1); r=2,3 -> co0+1
    const float bs0 = bias[co0], bs1 = bias[co0 + 1];
#pragma unroll
    for (int j = 0; j < 4; ++j) {
      const int n = j * 16 + l15;
      float v[4];
#pragma unroll
      for (int r = 0; r < 4; ++r) {
        float vv = acc[i][j][r] + ((r < 2) ? bs0 : bs1);
        vv = (vv < 0.f ? 0.01f * vv : vv) * kSqrt2;
        v[r] = fminf(fmaxf(vv, -256.f), 265.f);
      }
      float2* p0 = (float2*)&out[(((size_t)b * COUT + co0) * 128 + oh) * 128 + 2 * n];
      float2* p1 = (float2*)&out[(((size_t)b * COUT + co0 + 1) * 128 + oh) * 128 + 2 * n];
      *p0 = make_float2(v[0], v[1]);
      *p1 = make_float2(v[2], v[3]);
    }
  }
}

extern "C" void kernel_launch(void* const* d_in, const int* in_sizes, int n_in,
                              void* d_out, int out_size, void* d_ws, size_t ws_size,
                              hipStream_t stream) {
  const float* x = (const float*)d_in[0];
  const float* w = (const float*)d_in[1];
  const float* bias = (const float*)d_in[2];
  const float* f = (const float*)d_in[3];
  float* out = (float*)d_out;

  unsigned short* xb2 = (unsigned short*)d_ws;
  unsigned short* gw3 = (unsigned short*)((char*)d_ws + XB2_BYTES);

  hipLaunchKernelGGL(prep_all, dim3(900), dim3(256), 0, stream, x, w, f, xb2, gw3);
  hipLaunchKernelGGL(conv_main, dim3(512), dim3(256), 0, stream, xb2, gw3, bias, out);
}

// Round 19
// 76.426 us; speedup vs baseline: 2.0051x; 1.0048x over previous
//
#include <hip/hip_runtime.h>
#include <stdint.h>

#define CIN 256
#define COUT 128
#define BATCH 8
#define HH 64
#define WW 64
#define XROW 66

// xb2: padded bf16 input, [B][66 rows][66 cols][4 cb][8 slot][8 ch], slot pre-swizzled by (col&7)
#define XB2_BYTES ((size_t)BATCH * XROW * XROW * CIN * 2)
// gw3: fused weights, UNSWIZZLED: [9 taps][2 py][4 cb][256 row=co*2+px][8 g][8 ch]
#define GW3_BYTES ((size_t)9 * 2 * 4 * 256 * 64 * 2)

typedef __bf16 bf16x8 __attribute__((ext_vector_type(8)));
typedef float f32x4 __attribute__((ext_vector_type(4)));

__device__ __forceinline__ unsigned short f2bf(float f) {
  unsigned int u = __float_as_uint(f);
  u += 0x7fffu + ((u >> 16) & 1u);
  return (unsigned short)(u >> 16);
}

__device__ __forceinline__ void gload_lds16(const void* g, void* l) {
  __builtin_amdgcn_global_load_lds(
      (__attribute__((address_space(1))) void*)(uintptr_t)g,
      (__attribute__((address_space(3))) void*)l, 16, 0, 0);
}

// ---------------- fused prep: prep_x (512 blk) + prep_w (128 blk) + border (260 blk) ----------------
__global__ __launch_bounds__(256) void prep_all(const float* __restrict__ x,
                                                const float* __restrict__ w,
                                                const float* __restrict__ f,
                                                unsigned short* __restrict__ xb2,
                                                unsigned short* __restrict__ gw3) {
  __shared__ __align__(16) unsigned short lds[64][264];  // prep_x staging; fs aliases it
  const int blk = blockIdx.x;
  const int t = threadIdx.x;

  if (blk < 512) {
    // ---- prep_x: x -> padded channel-last swizzled bf16 (interior) ----
    int b = blk >> 6, iy = blk & 63;
    int cq = t >> 6, ix = t & 63;
    for (int ci = 0; ci < 64; ++ci) {
      int c = ci * 4 + cq;
      float v = x[(((size_t)b * CIN + c) * HH + iy) * WW + ix];
      lds[ix][c] = f2bf(v);
    }
    __syncthreads();
    for (int it = 0; it < 8; ++it) {
      int u = it * 256 + t;  // 2048 units of 16B: 64 ix * 32 (cb,slot)
      int ixo = u >> 5;
      int q = u & 31, cb = q >> 3, slot = q & 7;
      int col = ixo + 1;  // padded col
      int c0 = cb * 64 + 8 * (slot ^ (col & 7));
      uint4 val = *reinterpret_cast<const uint4*>(&lds[ixo][c0]);
      size_t o = ((((size_t)(b * XROW + (iy + 1)) * XROW + col) * 4 + cb) * 8 + slot) * 8;
      *reinterpret_cast<uint4*>(&xb2[o]) = val;
    }
  } else if (blk < 640) {
    // ---- prep_w: fuse He-scale * conv3x3 (x) FIR; stored UNSWIZZLED [row][g][8ch] ----
    float* fs = (float*)lds;
    int co = blk - 512;
    int c = t;
    if (c < 16) fs[c] = f[c];
    __syncthreads();
    float wl[3][3];
    const float he = 1.0f / 48.0f;  // 1/sqrt(256*9)
#pragma unroll
    for (int dy = 0; dy < 3; ++dy)
#pragma unroll
      for (int dx = 0; dx < 3; ++dx)
        wl[dy][dx] = w[((size_t)(co * CIN + c) * 3 + dy) * 3 + dx] * he;
    int cb = c >> 6, cl = c & 63;
    int g = cl >> 3;
    int ce = cl & 7;
    for (int d = 0; d < 3; ++d)
      for (int e = 0; e < 3; ++e)
        for (int py = 0; py < 2; ++py)
          for (int px = 0; px < 2; ++px) {
            int ty = 2 * d + 1 - py, tx = 2 * e + 1 - px;  // taps of 6x6 composite g
            float acc = 0.f;
            for (int dy = 0; dy < 3; ++dy) {
              int a = ty - dy;
              if (a < 0 || a > 3) continue;
              for (int dx = 0; dx < 3; ++dx) {
                int bb = tx - dx;
                if (bb < 0 || bb > 3) continue;
                acc += wl[dy][dx] * fs[a * 4 + bb];
              }
            }
            int row = co * 2 + px;
            size_t o =
                ((((size_t)(d * 3 + e) * 2 + py) * 4 + cb) * 256 + row) * 64 + g * 8 + ce;
            gw3[o] = f2bf(acc);
          }
  } else {
    // ---- border zeroing ----
    int u = (blk - 640) * 256 + t;
    if (u >= 66560) return;
    int b = u / 8320, v = u - b * 8320;
    int row, col, cs;
    if (v < 4224) {
      int rr = v / 2112;
      int rem = v - rr * 2112;
      row = rr * 65; col = rem >> 5; cs = rem & 31;
    } else {
      int v2 = v - 4224;
      row = 1 + (v2 >> 6);
      int rem = v2 & 63;
      col = (rem >> 5) * 65; cs = rem & 31;
    }
    size_t o = (((size_t)(b * XROW + row) * XROW + col) * 32 + cs) * 8;
    *reinterpret_cast<uint4*>(&xb2[o]) = make_uint4(0, 0, 0, 0);
  }
}

// ---------------- main: implicit-GEMM polyphase conv ----------------
// R16 geometry (BM=128/BN=256, 4 waves 1Mx4N, wave tile 128x64, A in two 8KB LDS
// k8-halves, X 50.7KB, 2 blocks/CU, in-place A restaging) + within-wave
// READ/MFMA interleave, with CORRECT sync ordering (R18's bug: buffer reads
// before the phase BAR race other waves' restage writes — per-wave vmcnt only
// drains MY writes; cross-wave visibility = drain -> BAR -> read):
//   phase: vmcnt(0) -> BAR -> {bv[4]+afr[0..1]} reads -> stage-issue ->
//          8 x {ds_read afr[i+2] | 4 MFMA} pinned by sched_group_barrier.
// Only ~200cy of head reads are exposed per phase; the other 6 af reads ride
// inside the MFMA stream (the measured serial profile: 1156cy LDS + 1241cy
// MFMA per phase). Buffer being restaged was last read in the PREVIOUS phase
// (lgkm-retired before this BAR); stage->drain gap stays >= 1 phase. Boundary
// X staging rides the same phase-top drain+BAR — exactly 2 barriers/step.
__global__ __launch_bounds__(256, 2) void conv_main(
    const unsigned short* __restrict__ xb2,
    const unsigned short* __restrict__ gw3,
    const float* __restrict__ bias,
    float* __restrict__ out) {
  __shared__ __align__(16) unsigned char smem[8192 + 8192 + 50688];
  unsigned short* ah0 = (unsigned short*)smem;            // A k8=0 half: [128 row][4 qp][16B]
  unsigned short* ah1 = (unsigned short*)(smem + 8192);   // A k8=1 half
  unsigned short* xt = (unsigned short*)(smem + 16384);   // X: [6 xrow][66 col][8 slot][16B]

  const int bid = blockIdx.x;
  const int b = bid & 7;              // XCD b-affinity
  const int mg = (bid >> 3) & 15;
  const int mb = (bid >> 7) & 1;      // weight-row half
  const int py = (bid >> 8) & 1;
  const int m0 = mg * 4;              // 4 output sub-rows per block

  const int t = threadIdx.x;
  const int lane = t & 63;
  const int wn = t >> 6;              // wave 0..3 = output sub-row
  const int l15 = lane & 15, l4 = lane >> 4;
  const int qpc = l4 ^ ((l15 >> 1) & 3);  // af physical slot (lane-constant)

  f32x4 acc[8][4] = {};

  const char* xbase = (const char*)xb2 + (size_t)((b * XROW + m0) * (XROW * 32)) * 16;
  const char* gw3b = (const char*)gw3 + mb * 16384;

  // stage one 8KB k8-half of A for tap (de,cb): 512 units, 2 gloads/thread.
#define STAGE_AH(DSTH, K8, de_, cb_)                                                   \
  do {                                                                                 \
    const char* g_ = gw3b + ((((size_t)(de_)*2 + py) * 4 + (cb_)) << 15);              \
    _Pragma("unroll") for (int it = 0; it < 2; ++it) {                                 \
      int u = it * 256 + t;                                                            \
      int lrow = u >> 2, qp = u & 3;                                                   \
      int gg = (K8)*4 + (qp ^ ((lrow >> 1) & 3));                                      \
      gload_lds16(g_ + lrow * 128 + gg * 16, (char*)(DSTH) + u * 16);                  \
    }                                                                                  \
  } while (0)

  // X tile per cb: 6 rows x 66 cols x 8 slots = 3168 16B units; 13 iters of 256
#define STAGE_X(cb_)                                                          \
  do {                                                                        \
    int rr_ = 0, rem_ = t;                                                    \
    for (int it = 0; it < 13; ++it) {                                         \
      int u = it * 256 + t;                                                   \
      if (u < 3168) {                                                         \
        int col = rem_ >> 3, slot = rem_ & 7;                                 \
        size_t go = (size_t)(rr_ * XROW + col) * 32 + (cb_)*8 + slot;         \
        gload_lds16(xbase + go * 16, (char*)xt + (size_t)u * 16);             \
      }                                                                       \
      rem_ += 256;                                                            \
      if (rem_ >= 528) { rem_ -= 528; ++rr_; }                                \
    }                                                                         \
  } while (0)

#define BAR()                        \
  do {                               \
    asm volatile("" ::: "memory");   \
    __builtin_amdgcn_s_barrier();    \
    asm volatile("" ::: "memory");   \
  } while (0)

  // single af fragment read (16-row group I of the half)
#define AF1(AH, I) \
  (*(const bf16x8*)((const char*)(AH) + (I)*1024 + l15 * 64 + qpc * 16))

#define READ_BV(BV, K8)                                                                \
  do {                                                                                 \
    _Pragma("unroll") for (int j = 0; j < 4; ++j) {                                    \
      int col = j * 16 + l15 + e;                                                      \
      int slot = ((K8)*4 + l4) ^ (col & 7);                                            \
      (BV)[j] = *(const bf16x8*)(xt + ((size_t)xr * 66 + col) * 64 + slot * 8);        \
    }                                                                                  \
  } while (0)

  // one phase: drain -> BAR -> head reads -> stage-issue -> 8 quads {1 ds_read | 4 MFMA}
#define PHASE(K8, AH, STAGE_STMT)                                                      \
  do {                                                                                 \
    bf16x8 bv[4], afr[8];                                                              \
    asm volatile("s_waitcnt vmcnt(0)" ::: "memory"); /* my stage writes landed */      \
    BAR();                                           /* ALL waves' writes landed */    \
    READ_BV(bv, K8);                                                                   \
    afr[0] = AF1(AH, 0);                                                               \
    afr[1] = AF1(AH, 1);                                                               \
    STAGE_STMT;                                                                        \
    __builtin_amdgcn_s_setprio(1);                                                     \
    _Pragma("unroll") for (int i = 0; i < 8; ++i) {                                    \
      if (i < 6) {                                                                     \
        afr[i + 2] = AF1(AH, i + 2);                                                   \
        __builtin_amdgcn_sched_group_barrier(0x100, 1, 0); /* 1 DS_READ */             \
      }                                                                                \
      _Pragma("unroll") for (int j = 0; j < 4; ++j)                                    \
        acc[i][j] = __builtin_amdgcn_mfma_f32_16x16x32_bf16(afr[i], bv[j],             \
                                                            acc[i][j], 0, 0, 0);      \
      __builtin_amdgcn_sched_group_barrier(0x8, 4, 0); /* 4 MFMA */                    \
    }                                                                                  \
    __builtin_amdgcn_s_setprio(0);                                                     \
  } while (0)

  // prologue: issue ah0 <- k0(0) and X(0); first phase's drain+BAR completes them
  STAGE_AH(ah0, 0, 0, 0);
  STAGE_X(0);

  int cb = 0, de = 0, d = 0, e = 0;
  for (int s = 0; s < 36; ++s) {
    const int xr = wn + d;
    const int notlast = (s < 35);
    const int nde = (de == 8) ? 0 : de + 1;
    const int ncb = (de == 8) ? cb + 1 : cb;
    const int ccb = (ncb > 3) ? 3 : ncb;
    const int boundary = (de == 8) && (cb < 3);

    // ph0: consume ah0=k0(s); stage ah1 <- k1(s) (read next phase, after drain+BAR)
    PHASE(0, ah0, { STAGE_AH(ah1, 1, de, cb); });

    // ph1: consume ah1=k1(s); stage ah0 <- k0(s+1) (+X at cb boundary);
    // next ph0's drain+BAR makes both visible to all waves before any read.
    PHASE(1, ah1, {
      if (boundary) STAGE_X(cb + 1);
      if (notlast) STAGE_AH(ah0, 0, nde, ccb);
    });

    d = (nde == 0) ? 0 : ((e == 2) ? d + 1 : d);
    e = (nde == 0) ? 0 : ((e == 2) ? 0 : e + 1);
    de = nde; cb = ncb;
  }
#undef STAGE_AH
#undef STAGE_X
#undef AF1
#undef READ_BV
#undef PHASE

  const float kSqrt2 = 1.41421356237309515f;
  const int oh = 2 * (m0 + wn) + py;
#pragma unroll
  for (int i = 0; i < 8; ++i) {
    const int row0 = mb * 128 + i * 16 + l4 * 4;  // even
    const int co0 = row0 >> 1;                    // r=0,1 -> co0 (px=0,1); r=2,3 -> co0+1
    const float bs0 = bias[co0], bs1 = bias[co0 + 1];
#pragma unroll
    for (int j = 0; j < 4; ++j) {
      const int n = j * 16 + l15;
      float v[4];
#pragma unroll
      for (int r = 0; r < 4; ++r) {
        float vv = acc[i][j][r] + ((r < 2) ? bs0 : bs1);
        vv = (vv < 0.f ? 0.01f * vv : vv) * kSqrt2;
        v[r] = fminf(fmaxf(vv, -256.f), 265.f);
      }
      float2* p0 = (float2*)&out[(((size_t)b * COUT + co0) * 128 + oh) * 128 + 2 * n];
      float2* p1 = (float2*)&out[(((size_t)b * COUT + co0 + 1) * 128 + oh) * 128 + 2 * n];
      *p0 = make_float2(v[0], v[1]);
      *p1 = make_float2(v[2], v[3]);
    }
  }
}

extern "C" void kernel_launch(void* const* d_in, const int* in_sizes, int n_in,
                              void* d_out, int out_size, void* d_ws, size_t ws_size,
                              hipStream_t stream) {
  const float* x = (const float*)d_in[0];
  const float* w = (const float*)d_in[1];
  const float* bias = (const float*)d_in[2];
  const float* f = (const float*)d_in[3];
  float* out = (float*)d_out;

  unsigned short* xb2 = (unsigned short*)d_ws;
  unsigned short* gw3 = (unsigned short*)((char*)d_ws + XB2_BYTES);

  hipLaunchKernelGGL(prep_all, dim3(900), dim3(256), 0, stream, x, w, f, xb2, gw3);
  hipLaunchKernelGGL(conv_main, dim3(512), dim3(256), 0, stream, xb2, gw3, bias, out);
}